// Round 12
// baseline (3295.842 us; speedup 1.0000x reference)
//
#include <hip/hip_runtime.h>

// ---------------------------------------------------------------------------
// RNN_69526930588180: 3-layer SimpleRNN (tanh), B=256, T=256, D=64, H=512.
//
// Round 12 = round 11 + compile fix (s_sleep needs a constant arg).
// Round 11 idea: r9 layer-wavefront pipeline (1286us, best) with the
// counter-line saturation removed:
//  * every counter padded to its own 64B line (r9 packed 16 counters/line ->
//    pollers of t-1, pollers of t, publishers of t all serialized on one
//    line's atomic queue; ~3.5us of the 4.8us hop).
//  * fast-path polls are plain sc0 LOADS (L2 read path, no atomic-unit
//    serialization; same-XCD atomics land in the shared L2 which sc0 loads
//    read). Safety: escalate to the r6-proven RMW read after 64 failed
//    iterations -> bounded cost even if plain-load polling were ever stale.
//  * poll backoff: 4 busy iters, then s_sleep(1); s_sleep(2) after escalation.
// Everything else verbatim r9: 192 WGs = 3 layers x 8 bg x 8 cg; rec waves
// poll own layer t-1, proj waves poll layer l-1 at t; fast(same-XCD)=sc0,
// slow=sc0 sc1; XCC_ID handshake; Cbuf parity; one barrier/step.
// ---------------------------------------------------------------------------

typedef unsigned short u16;
typedef unsigned int   u32;

typedef __attribute__((ext_vector_type(8))) short short8;
typedef __attribute__((ext_vector_type(4))) float f32x4;
typedef __attribute__((ext_vector_type(4))) int   i32x4;

#define N_B 256
#define N_T 256
#define N_D 64
#define N_H 512
#define LAY 3
#define BG  8     // batch groups (32 rows each)
#define CGS 8     // col groups (64 cols each)
#define ROWS 32   // rows per bg
#define WCOL 64   // cols per WG
#define CNT_TGT 16   // 8 WGs x 2 rec waves publish per (layer,bg,t)
#define HSK_TGT 24   // 3 layers x 8 cg WGs per bg
#define CPAD 16      // u32 per counter (64B line)
// counter region: [LAY*BG*N_T] lines; then hsk arrive [BG] lines, mask [BG] lines
#define CNT_LINES (LAY * BG * N_T)
#define CNT_U32   ((CNT_LINES + 2 * BG) * CPAD)

__device__ __forceinline__ u16 f2bf(float f) {
  union { float f; u32 u; } v; v.f = f;
  u32 u = v.u;
  u += 0x7fffu + ((u >> 16) & 1u);   // RNE
  return (u16)(u >> 16);
}
__device__ __forceinline__ float bf2f(u16 h) {
  union { u32 u; float f; } v; v.u = ((u32)h) << 16;
  return v.f;
}
__device__ __forceinline__ short8 ld8(const u16* p) { return *(const short8*)p; }
__device__ __forceinline__ short8 cvt8(const float* p) {
  short8 r;
#pragma unroll
  for (int j = 0; j < 8; ++j) r[j] = (short)f2bf(p[j]);
  return r;
}
__device__ __forceinline__ short8 as_s8(i32x4 v) {
  union { i32x4 i; short8 s; } u; u.i = v; return u.s;
}
__device__ __forceinline__ float fast_tanh(float x) {
  float xc = fminf(fmaxf(x, -9.f), 9.f);
  float e  = __builtin_amdgcn_exp2f(xc * 2.8853900817779268f);
  return 1.f - 2.f * __builtin_amdgcn_rcpf(e + 1.f);
}
// FIFO-fair coherence-point read (r6/r8/r9-proven). Escalation fallback.
__device__ __forceinline__ u32 rmw_read(u32* p) {
  u32 v, z = 0;
  asm volatile("global_atomic_add %0, %1, %2, off sc0\n\ts_waitcnt vmcnt(0)"
               : "=v"(v) : "v"(p), "v"(z) : "memory");
  return v;
}
__device__ __forceinline__ u32 ld_sc0(const u32* p) {
  u32 v;
  asm volatile("global_load_dword %0, %1, off sc0\n\ts_waitcnt vmcnt(0)"
               : "=v"(v) : "v"(p) : "memory");
  return v;
}
// Wait until *cp >= target. Fast path: plain sc0 loads, escalate to RMW
// after 64 iters (safety vs stale-line livelock); slow path: agent atomic load.
__device__ __forceinline__ void poll_cnt(u32* cp, u32 target, bool fast, bool* dead) {
  u32 it = 0;
  for (;;) {
    u32 v;
    if (!fast) {
      v = __hip_atomic_load(cp, __ATOMIC_RELAXED, __HIP_MEMORY_SCOPE_AGENT);
    } else if (it < 64) {
      v = ld_sc0(cp);
    } else {
      v = rmw_read(cp);
    }
    if (v >= target) return;
    if (it >= 64) {
      __builtin_amdgcn_s_sleep(2);
    } else if (it >= 4) {
      __builtin_amdgcn_s_sleep(1);
    }
    if (++it > (1u << 22)) { *dead = true; return; }
  }
}

// 16 batched A-fragment loads (row fixed, k = kt*32 + quad*8), one vmcnt.
__device__ __forceinline__ void load_frags16_fast(const u16* p, i32x4 f[16]) {
  asm volatile(
      "global_load_dwordx4 %0, %16, off sc0\n\t"
      "global_load_dwordx4 %1, %16, off offset:64 sc0\n\t"
      "global_load_dwordx4 %2, %16, off offset:128 sc0\n\t"
      "global_load_dwordx4 %3, %16, off offset:192 sc0\n\t"
      "global_load_dwordx4 %4, %16, off offset:256 sc0\n\t"
      "global_load_dwordx4 %5, %16, off offset:320 sc0\n\t"
      "global_load_dwordx4 %6, %16, off offset:384 sc0\n\t"
      "global_load_dwordx4 %7, %16, off offset:448 sc0\n\t"
      "global_load_dwordx4 %8, %16, off offset:512 sc0\n\t"
      "global_load_dwordx4 %9, %16, off offset:576 sc0\n\t"
      "global_load_dwordx4 %10, %16, off offset:640 sc0\n\t"
      "global_load_dwordx4 %11, %16, off offset:704 sc0\n\t"
      "global_load_dwordx4 %12, %16, off offset:768 sc0\n\t"
      "global_load_dwordx4 %13, %16, off offset:832 sc0\n\t"
      "global_load_dwordx4 %14, %16, off offset:896 sc0\n\t"
      "global_load_dwordx4 %15, %16, off offset:960 sc0\n\t"
      "s_waitcnt vmcnt(0)"
      : "=&v"(f[0]), "=&v"(f[1]), "=&v"(f[2]), "=&v"(f[3]),
        "=&v"(f[4]), "=&v"(f[5]), "=&v"(f[6]), "=&v"(f[7]),
        "=&v"(f[8]), "=&v"(f[9]), "=&v"(f[10]), "=&v"(f[11]),
        "=&v"(f[12]), "=&v"(f[13]), "=&v"(f[14]), "=&v"(f[15])
      : "v"(p) : "memory");
}
__device__ __forceinline__ void load_frags16_slow(const u16* p, i32x4 f[16]) {
  asm volatile(
      "global_load_dwordx4 %0, %16, off sc0 sc1\n\t"
      "global_load_dwordx4 %1, %16, off offset:64 sc0 sc1\n\t"
      "global_load_dwordx4 %2, %16, off offset:128 sc0 sc1\n\t"
      "global_load_dwordx4 %3, %16, off offset:192 sc0 sc1\n\t"
      "global_load_dwordx4 %4, %16, off offset:256 sc0 sc1\n\t"
      "global_load_dwordx4 %5, %16, off offset:320 sc0 sc1\n\t"
      "global_load_dwordx4 %6, %16, off offset:384 sc0 sc1\n\t"
      "global_load_dwordx4 %7, %16, off offset:448 sc0 sc1\n\t"
      "global_load_dwordx4 %8, %16, off offset:512 sc0 sc1\n\t"
      "global_load_dwordx4 %9, %16, off offset:576 sc0 sc1\n\t"
      "global_load_dwordx4 %10, %16, off offset:640 sc0 sc1\n\t"
      "global_load_dwordx4 %11, %16, off offset:704 sc0 sc1\n\t"
      "global_load_dwordx4 %12, %16, off offset:768 sc0 sc1\n\t"
      "global_load_dwordx4 %13, %16, off offset:832 sc0 sc1\n\t"
      "global_load_dwordx4 %14, %16, off offset:896 sc0 sc1\n\t"
      "global_load_dwordx4 %15, %16, off offset:960 sc0 sc1\n\t"
      "s_waitcnt vmcnt(0)"
      : "=&v"(f[0]), "=&v"(f[1]), "=&v"(f[2]), "=&v"(f[3]),
        "=&v"(f[4]), "=&v"(f[5]), "=&v"(f[6]), "=&v"(f[7]),
        "=&v"(f[8]), "=&v"(f[9]), "=&v"(f[10]), "=&v"(f[11]),
        "=&v"(f[12]), "=&v"(f[13]), "=&v"(f[14]), "=&v"(f[15])
      : "v"(p) : "memory");
}

#define MFMA16(a, b, c) __builtin_amdgcn_mfma_f32_16x16x32_bf16((a), (b), (c), 0, 0, 0)

// All 3 layers in one persistent kernel (layer-wavefront pipeline).
__global__ __launch_bounds__(256, 1)
void rnn_pipe(const float* __restrict__ x,
              const float* __restrict__ Wx0, const float* __restrict__ Wh0, const float* __restrict__ b0,
              const float* __restrict__ Wx1, const float* __restrict__ Wh1, const float* __restrict__ b1,
              const float* __restrict__ Wx2, const float* __restrict__ Wh2, const float* __restrict__ b2,
              u16* __restrict__ seq0, u16* __restrict__ seq1, u16* __restrict__ seq2,
              u32* __restrict__ cnt) {
  const int b    = blockIdx.x & 7;          // batch group (XCD under %8 rr)
  const int rst  = blockIdx.x >> 3;         // 0..23
  const int layer = rst >> 3;               // 0..2
  const int j    = rst & 7;                 // col group
  const int tid  = threadIdx.x;
  const int lane = tid & 63;
  const int w    = tid >> 6;                // 0-1 rec, 2-3 proj
  const int quad = lane >> 4;
  const int l16  = lane & 15;
  const int half = w & 1;                   // 16-row sub-tile
  const bool is_rec = (w < 2);

  const float *Wx, *Wh, *bias; const u16 *in_seq = nullptr; u16 *out_seq;
  if (layer == 0)      { Wx = Wx0; Wh = Wh0; bias = b0; out_seq = seq0; }
  else if (layer == 1) { Wx = Wx1; Wh = Wh1; bias = b1; in_seq = seq0; out_seq = seq1; }
  else                 { Wx = Wx2; Wh = Wh2; bias = b2; in_seq = seq1; out_seq = seq2; }
  const int kin = (layer == 0) ? N_D : N_H;
  u32* cnt_own  = cnt + (size_t)(layer * BG + b) * N_T * CPAD;
  u32* cnt_prev = (layer > 0) ? cnt + (size_t)((layer - 1) * BG + b) * N_T * CPAD : nullptr;
  u32* hsk_arr  = cnt + (size_t)(CNT_LINES + b) * CPAD;
  u32* hsk_msk  = cnt + (size_t)(CNT_LINES + BG + b) * CPAD;

  __shared__ u16   WhT[WCOL][N_H];     // [n][k], k rotated by 8*n
  __shared__ u16   WxT[WCOL][N_H];     // layer0 uses only [.][0..63]
  __shared__ float Cbuf[2][ROWS][WCOL + 1];
  __shared__ u32   fastsh;

  // ---- startup handshake: all 24 WGs of bg b on one XCD? ----
  u32 xcc;
  asm volatile("s_getreg_b32 %0, hwreg(HW_REG_XCC_ID)" : "=s"(xcc));
  if (tid == 0) {
    __hip_atomic_fetch_or(hsk_msk, 1u << (xcc & 7), __ATOMIC_RELAXED,
                          __HIP_MEMORY_SCOPE_AGENT);
    asm volatile("s_waitcnt vmcnt(0)" ::: "memory");
    __hip_atomic_fetch_add(hsk_arr, 1u, __ATOMIC_RELAXED, __HIP_MEMORY_SCOPE_AGENT);
  }

  // Stage weight slices (cols j*64..+64) while the handshake propagates.
  for (int e = tid; e < WCOL * N_H; e += 256) {
    int n = e & 63, k = e >> 6;
    WhT[n][(k + 8 * n) & (N_H - 1)] = f2bf(Wh[k * N_H + j * WCOL + n]);
  }
  for (int e = tid; e < WCOL * kin; e += 256) {
    int n = e & 63, k = e >> 6;
    WxT[n][(k + 8 * n) & (kin - 1)] = f2bf(Wx[k * N_H + j * WCOL + n]);
  }
  float bv[4];
#pragma unroll
  for (int n = 0; n < 4; ++n) bv[n] = bias[j * WCOL + n * 16 + l16];

  if (tid == 0) {
    bool f = false;
    u32 it = 0;
    while (rmw_read(hsk_arr) < (u32)HSK_TGT) {
      __builtin_amdgcn_s_sleep(1);
      if (++it > (1u << 22)) break;
    }
    if (it <= (1u << 22)) {
      u32 m = rmw_read(hsk_msk);
      f = (m != 0u) && ((m & (m - 1u)) == 0u);
    }
    fastsh = f ? 1u : 0u;
  }
  __syncthreads();
  const bool fast = (fastsh == 1u);

  const int arow = b * ROWS + half * 16 + l16;  // this lane's A-row
  bool dead = false;

  for (int t = 0; t < N_T; ++t) {
    const int par = t & 1;
    f32x4 acc[4] = {{0.f,0.f,0.f,0.f},{0.f,0.f,0.f,0.f},{0.f,0.f,0.f,0.f},{0.f,0.f,0.f,0.f}};

    if (!is_rec) {
      // ---- proj waves: (layer0: x_t@Wx) / (else: h_{l-1}(t)@Wx) -> Cbuf ----
      if (layer == 0) {
        const float* xp = x + ((size_t)arow * N_T + t) * N_D + quad * 8;
        short8 f0 = cvt8(xp), f1 = cvt8(xp + 32);
#pragma unroll
        for (int n = 0; n < 4; ++n) {
          int nl = n * 16 + l16;
          acc[n] = MFMA16(f0, ld8(&WxT[nl][(quad * 8 + 8 * nl) & (N_D - 1)]), acc[n]);
          acc[n] = MFMA16(f1, ld8(&WxT[nl][(32 + quad * 8 + 8 * nl) & (N_D - 1)]), acc[n]);
        }
      } else {
        // wait for layer l-1 to publish h(t)
        if (lane == 0 && !dead)
          poll_cnt(cnt_prev + (size_t)t * CPAD, CNT_TGT, fast, &dead);
        const u16* sp = in_seq + ((size_t)t * N_B + arow) * N_H + quad * 8;
        i32x4 fr[16];
        if (fast) load_frags16_fast(sp, fr);
        else      load_frags16_slow(sp, fr);
#pragma unroll
        for (int kt = 0; kt < 16; ++kt) {
          short8 a = as_s8(fr[kt]);
#pragma unroll
          for (int n = 0; n < 4; ++n) {
            int nl = n * 16 + l16;
            acc[n] = MFMA16(a, ld8(&WxT[nl][(kt * 32 + quad * 8 + 8 * nl) & (N_H - 1)]), acc[n]);
          }
        }
      }
      // write proj partials to Cbuf[par]
      int rb = half * 16 + quad * 4;
#pragma unroll
      for (int n = 0; n < 4; ++n)
#pragma unroll
        for (int r = 0; r < 4; ++r)
          Cbuf[par][rb + r][n * 16 + l16] = acc[n][r];
    } else {
      // ---- rec waves: wait own layer t-1, load A, h@Wh ----
      if (t > 0) {
        if (lane == 0 && !dead)
          poll_cnt(cnt_own + (size_t)(t - 1) * CPAD, CNT_TGT, fast, &dead);
        const u16* ap = out_seq + ((size_t)(t - 1) * N_B + arow) * N_H + quad * 8;
        i32x4 fr[16];
        if (fast) load_frags16_fast(ap, fr);
        else      load_frags16_slow(ap, fr);
#pragma unroll
        for (int kt = 0; kt < 16; ++kt) {
          short8 a = as_s8(fr[kt]);
#pragma unroll
          for (int n = 0; n < 4; ++n) {
            int nl = n * 16 + l16;
            acc[n] = MFMA16(a, ld8(&WhT[nl][(kt * 32 + quad * 8 + 8 * nl) & (N_H - 1)]), acc[n]);
          }
        }
      }
    }

    __syncthreads();  // the only per-step barrier: Cbuf[par] ready

    if (is_rec) {
      // ---- combine + tanh + store h + publish ----
      int rb = half * 16 + quad * 4;
      u32 hv[4][4];
#pragma unroll
      for (int n = 0; n < 4; ++n)
#pragma unroll
        for (int r = 0; r < 4; ++r)
          hv[n][r] = (u32)f2bf(fast_tanh(acc[n][r] + Cbuf[par][rb + r][n * 16 + l16] + bv[n]));
      // lane addr: row = b*32 + half*16 + quad*4 (+r), col = j*64 + l16 (+n*16)
      u16* hdst = out_seq + ((size_t)t * N_B + b * ROWS + half * 16 + quad * 4) * N_H
                  + j * WCOL + l16;
      if (fast) {
        asm volatile(
            "global_store_short %0, %1, off sc0\n\t"
            "global_store_short %0, %2, off offset:1024 sc0\n\t"
            "global_store_short %0, %3, off offset:2048 sc0\n\t"
            "global_store_short %0, %4, off offset:3072 sc0\n\t"
            "global_store_short %0, %5, off offset:32 sc0\n\t"
            "global_store_short %0, %6, off offset:1056 sc0\n\t"
            "global_store_short %0, %7, off offset:2080 sc0\n\t"
            "global_store_short %0, %8, off offset:3104 sc0\n\t"
            "global_store_short %0, %9, off offset:64 sc0\n\t"
            "global_store_short %0, %10, off offset:1088 sc0\n\t"
            "global_store_short %0, %11, off offset:2112 sc0\n\t"
            "global_store_short %0, %12, off offset:3136 sc0\n\t"
            "global_store_short %0, %13, off offset:96 sc0\n\t"
            "global_store_short %0, %14, off offset:1120 sc0\n\t"
            "global_store_short %0, %15, off offset:2144 sc0\n\t"
            "global_store_short %0, %16, off offset:3168 sc0"
            :: "v"(hdst),
               "v"(hv[0][0]), "v"(hv[0][1]), "v"(hv[0][2]), "v"(hv[0][3]),
               "v"(hv[1][0]), "v"(hv[1][1]), "v"(hv[1][2]), "v"(hv[1][3]),
               "v"(hv[2][0]), "v"(hv[2][1]), "v"(hv[2][2]), "v"(hv[2][3]),
               "v"(hv[3][0]), "v"(hv[3][1]), "v"(hv[3][2]), "v"(hv[3][3])
            : "memory");
      } else {
        asm volatile(
            "global_store_short %0, %1, off sc0 sc1\n\t"
            "global_store_short %0, %2, off offset:1024 sc0 sc1\n\t"
            "global_store_short %0, %3, off offset:2048 sc0 sc1\n\t"
            "global_store_short %0, %4, off offset:3072 sc0 sc1\n\t"
            "global_store_short %0, %5, off offset:32 sc0 sc1\n\t"
            "global_store_short %0, %6, off offset:1056 sc0 sc1\n\t"
            "global_store_short %0, %7, off offset:2080 sc0 sc1\n\t"
            "global_store_short %0, %8, off offset:3104 sc0 sc1\n\t"
            "global_store_short %0, %9, off offset:64 sc0 sc1\n\t"
            "global_store_short %0, %10, off offset:1088 sc0 sc1\n\t"
            "global_store_short %0, %11, off offset:2112 sc0 sc1\n\t"
            "global_store_short %0, %12, off offset:3136 sc0 sc1\n\t"
            "global_store_short %0, %13, off offset:96 sc0 sc1\n\t"
            "global_store_short %0, %14, off offset:1120 sc0 sc1\n\t"
            "global_store_short %0, %15, off offset:2144 sc0 sc1\n\t"
            "global_store_short %0, %16, off offset:3168 sc0 sc1"
            :: "v"(hdst),
               "v"(hv[0][0]), "v"(hv[0][1]), "v"(hv[0][2]), "v"(hv[0][3]),
               "v"(hv[1][0]), "v"(hv[1][1]), "v"(hv[1][2]), "v"(hv[1][3]),
               "v"(hv[2][0]), "v"(hv[2][1]), "v"(hv[2][2]), "v"(hv[2][3]),
               "v"(hv[3][0]), "v"(hv[3][1]), "v"(hv[3][2]), "v"(hv[3][3])
            : "memory");
      }
      asm volatile("s_waitcnt vmcnt(0)" ::: "memory");
      if (lane == 0) {
        u32* cp = cnt_own + (size_t)t * CPAD;
        if (fast) {
          u32 one = 1u;
          asm volatile("global_atomic_add %0, %1, off" :: "v"(cp), "v"(one) : "memory");
        } else {
          __hip_atomic_fetch_add(cp, 1u, __ATOMIC_RELAXED, __HIP_MEMORY_SCOPE_AGENT);
        }
      }
    }
    // no trailing barrier: Cbuf parity + next barrier handle WAR (r8/r9-proven)
  }
}

// out[b] = seq2[T-1][b][:] . Wf + bf
__global__ void head_kernel(const u16* __restrict__ seq2, const float* __restrict__ Wf,
                            const float* __restrict__ bf, float* __restrict__ out) {
  int b    = blockIdx.x;
  int lane = threadIdx.x;  // 64
  const u16* hrow = seq2 + ((size_t)(N_T - 1) * N_B + b) * N_H;
  float s = 0.f;
#pragma unroll
  for (int r = 0; r < N_H / 64; ++r) {
    int idx = lane * 8 + r;
    s += bf2f(hrow[idx]) * Wf[idx];
  }
#pragma unroll
  for (int off = 32; off > 0; off >>= 1) s += __shfl_down(s, off);
  if (lane == 0) out[b] = s + bf[0];
}

extern "C" void kernel_launch(void* const* d_in, const int* in_sizes, int n_in,
                              void* d_out, int out_size, void* d_ws, size_t ws_size,
                              hipStream_t stream) {
  const float* x   = (const float*)d_in[0];
  const float* Wx0 = (const float*)d_in[1];
  const float* Wh0 = (const float*)d_in[2];
  const float* b0  = (const float*)d_in[3];
  const float* Wx1 = (const float*)d_in[4];
  const float* Wh1 = (const float*)d_in[5];
  const float* b1  = (const float*)d_in[6];
  const float* Wx2 = (const float*)d_in[7];
  const float* Wh2 = (const float*)d_in[8];
  const float* b2  = (const float*)d_in[9];
  const float* Wf  = (const float*)d_in[10];
  const float* bf  = (const float*)d_in[11];
  float* out = (float*)d_out;

  const size_t SEQ_BYTES = (size_t)N_T * N_B * N_H * sizeof(u16);  // 67,108,864
  if (ws_size < 3 * SEQ_BYTES + (size_t)CNT_U32 * sizeof(u32)) return;

  char* ws  = (char*)d_ws;
  u16* seq0 = (u16*)(ws);
  u16* seq1 = (u16*)(ws + SEQ_BYTES);
  u16* seq2 = (u16*)(ws + 2 * SEQ_BYTES);
  u32* cnt  = (u32*)(ws + 3 * SEQ_BYTES);

  (void)hipMemsetAsync(cnt, 0, (size_t)CNT_U32 * sizeof(u32), stream);

  rnn_pipe<<<LAY * BG * CGS, 256, 0, stream>>>(x, Wx0, Wh0, b0, Wx1, Wh1, b1,
                                               Wx2, Wh2, b2, seq0, seq1, seq2,
                                               cnt);
  head_kernel<<<N_B, 64, 0, stream>>>(seq2, Wf, bf, out);
}

// Round 13
// 1232.211 us; speedup vs baseline: 2.6747x; 2.6747x over previous
//
#include <hip/hip_runtime.h>

// ---------------------------------------------------------------------------
// RNN_69526930588180: 3-layer SimpleRNN (tanh), B=256, T=256, D=64, H=512.
//
// Round 13 = round 9 (layer-wavefront pipeline, 1286us best) + ONE change:
// counters padded to their own 64B lines. r12 proved plain-sc0-load polling
// is STALE on this fabric (hop 4.8 -> 12.8us, all idle counters down); polls
// revert to the r6/r9-proven FIFO-fair RMW reads (both sides of a polled
// signal must go through the atomic unit: r7 = store-side failure, r12 =
// load-side failure). Padding removes poller(t-1)/publisher(t) serialization
// on a shared counter line (16 counters/line in r9).
// Everything else verbatim r9: 192 WGs = 3 layers x 8 bg x 8 cg; rec waves
// poll own layer t-1, proj waves poll layer l-1 at t; fast(same-XCD)=sc0,
// slow=sc0 sc1; XCC_ID handshake; Cbuf parity; one barrier/step.
// ---------------------------------------------------------------------------

typedef unsigned short u16;
typedef unsigned int   u32;

typedef __attribute__((ext_vector_type(8))) short short8;
typedef __attribute__((ext_vector_type(4))) float f32x4;
typedef __attribute__((ext_vector_type(4))) int   i32x4;

#define N_B 256
#define N_T 256
#define N_D 64
#define N_H 512
#define LAY 3
#define BG  8     // batch groups (32 rows each)
#define CGS 8     // col groups (64 cols each)
#define ROWS 32   // rows per bg
#define WCOL 64   // cols per WG
#define CNT_TGT 16   // 8 WGs x 2 rec waves publish per (layer,bg,t)
#define HSK_TGT 24   // 3 layers x 8 cg WGs per bg
#define CPAD 16      // u32 per counter (64B line)
#define CNT_LINES (LAY * BG * N_T)
#define CNT_U32   ((CNT_LINES + 2 * BG) * CPAD)

__device__ __forceinline__ u16 f2bf(float f) {
  union { float f; u32 u; } v; v.f = f;
  u32 u = v.u;
  u += 0x7fffu + ((u >> 16) & 1u);   // RNE
  return (u16)(u >> 16);
}
__device__ __forceinline__ float bf2f(u16 h) {
  union { u32 u; float f; } v; v.u = ((u32)h) << 16;
  return v.f;
}
__device__ __forceinline__ short8 ld8(const u16* p) { return *(const short8*)p; }
__device__ __forceinline__ short8 cvt8(const float* p) {
  short8 r;
#pragma unroll
  for (int j = 0; j < 8; ++j) r[j] = (short)f2bf(p[j]);
  return r;
}
__device__ __forceinline__ short8 as_s8(i32x4 v) {
  union { i32x4 i; short8 s; } u; u.i = v; return u.s;
}
__device__ __forceinline__ float fast_tanh(float x) {
  float xc = fminf(fmaxf(x, -9.f), 9.f);
  float e  = __builtin_amdgcn_exp2f(xc * 2.8853900817779268f);
  return 1.f - 2.f * __builtin_amdgcn_rcpf(e + 1.f);
}
// FIFO-fair coherence-point read (r6/r8/r9-proven). The ONLY safe poll.
__device__ __forceinline__ u32 rmw_read(u32* p) {
  u32 v, z = 0;
  asm volatile("global_atomic_add %0, %1, %2, off sc0\n\ts_waitcnt vmcnt(0)"
               : "=v"(v) : "v"(p), "v"(z) : "memory");
  return v;
}

// 16 batched A-fragment loads (row fixed, k = kt*32 + quad*8), one vmcnt.
__device__ __forceinline__ void load_frags16_fast(const u16* p, i32x4 f[16]) {
  asm volatile(
      "global_load_dwordx4 %0, %16, off sc0\n\t"
      "global_load_dwordx4 %1, %16, off offset:64 sc0\n\t"
      "global_load_dwordx4 %2, %16, off offset:128 sc0\n\t"
      "global_load_dwordx4 %3, %16, off offset:192 sc0\n\t"
      "global_load_dwordx4 %4, %16, off offset:256 sc0\n\t"
      "global_load_dwordx4 %5, %16, off offset:320 sc0\n\t"
      "global_load_dwordx4 %6, %16, off offset:384 sc0\n\t"
      "global_load_dwordx4 %7, %16, off offset:448 sc0\n\t"
      "global_load_dwordx4 %8, %16, off offset:512 sc0\n\t"
      "global_load_dwordx4 %9, %16, off offset:576 sc0\n\t"
      "global_load_dwordx4 %10, %16, off offset:640 sc0\n\t"
      "global_load_dwordx4 %11, %16, off offset:704 sc0\n\t"
      "global_load_dwordx4 %12, %16, off offset:768 sc0\n\t"
      "global_load_dwordx4 %13, %16, off offset:832 sc0\n\t"
      "global_load_dwordx4 %14, %16, off offset:896 sc0\n\t"
      "global_load_dwordx4 %15, %16, off offset:960 sc0\n\t"
      "s_waitcnt vmcnt(0)"
      : "=&v"(f[0]), "=&v"(f[1]), "=&v"(f[2]), "=&v"(f[3]),
        "=&v"(f[4]), "=&v"(f[5]), "=&v"(f[6]), "=&v"(f[7]),
        "=&v"(f[8]), "=&v"(f[9]), "=&v"(f[10]), "=&v"(f[11]),
        "=&v"(f[12]), "=&v"(f[13]), "=&v"(f[14]), "=&v"(f[15])
      : "v"(p) : "memory");
}
__device__ __forceinline__ void load_frags16_slow(const u16* p, i32x4 f[16]) {
  asm volatile(
      "global_load_dwordx4 %0, %16, off sc0 sc1\n\t"
      "global_load_dwordx4 %1, %16, off offset:64 sc0 sc1\n\t"
      "global_load_dwordx4 %2, %16, off offset:128 sc0 sc1\n\t"
      "global_load_dwordx4 %3, %16, off offset:192 sc0 sc1\n\t"
      "global_load_dwordx4 %4, %16, off offset:256 sc0 sc1\n\t"
      "global_load_dwordx4 %5, %16, off offset:320 sc0 sc1\n\t"
      "global_load_dwordx4 %6, %16, off offset:384 sc0 sc1\n\t"
      "global_load_dwordx4 %7, %16, off offset:448 sc0 sc1\n\t"
      "global_load_dwordx4 %8, %16, off offset:512 sc0 sc1\n\t"
      "global_load_dwordx4 %9, %16, off offset:576 sc0 sc1\n\t"
      "global_load_dwordx4 %10, %16, off offset:640 sc0 sc1\n\t"
      "global_load_dwordx4 %11, %16, off offset:704 sc0 sc1\n\t"
      "global_load_dwordx4 %12, %16, off offset:768 sc0 sc1\n\t"
      "global_load_dwordx4 %13, %16, off offset:832 sc0 sc1\n\t"
      "global_load_dwordx4 %14, %16, off offset:896 sc0 sc1\n\t"
      "global_load_dwordx4 %15, %16, off offset:960 sc0 sc1\n\t"
      "s_waitcnt vmcnt(0)"
      : "=&v"(f[0]), "=&v"(f[1]), "=&v"(f[2]), "=&v"(f[3]),
        "=&v"(f[4]), "=&v"(f[5]), "=&v"(f[6]), "=&v"(f[7]),
        "=&v"(f[8]), "=&v"(f[9]), "=&v"(f[10]), "=&v"(f[11]),
        "=&v"(f[12]), "=&v"(f[13]), "=&v"(f[14]), "=&v"(f[15])
      : "v"(p) : "memory");
}

#define MFMA16(a, b, c) __builtin_amdgcn_mfma_f32_16x16x32_bf16((a), (b), (c), 0, 0, 0)

// All 3 layers in one persistent kernel (layer-wavefront pipeline).
__global__ __launch_bounds__(256, 1)
void rnn_pipe(const float* __restrict__ x,
              const float* __restrict__ Wx0, const float* __restrict__ Wh0, const float* __restrict__ b0,
              const float* __restrict__ Wx1, const float* __restrict__ Wh1, const float* __restrict__ b1,
              const float* __restrict__ Wx2, const float* __restrict__ Wh2, const float* __restrict__ b2,
              u16* __restrict__ seq0, u16* __restrict__ seq1, u16* __restrict__ seq2,
              u32* __restrict__ cnt) {
  const int b    = blockIdx.x & 7;          // batch group (XCD under %8 rr)
  const int rst  = blockIdx.x >> 3;         // 0..23
  const int layer = rst >> 3;               // 0..2
  const int j    = rst & 7;                 // col group
  const int tid  = threadIdx.x;
  const int lane = tid & 63;
  const int w    = tid >> 6;                // 0-1 rec, 2-3 proj
  const int quad = lane >> 4;
  const int l16  = lane & 15;
  const int half = w & 1;                   // 16-row sub-tile
  const bool is_rec = (w < 2);

  const float *Wx, *Wh, *bias; const u16 *in_seq = nullptr; u16 *out_seq;
  if (layer == 0)      { Wx = Wx0; Wh = Wh0; bias = b0; out_seq = seq0; }
  else if (layer == 1) { Wx = Wx1; Wh = Wh1; bias = b1; in_seq = seq0; out_seq = seq1; }
  else                 { Wx = Wx2; Wh = Wh2; bias = b2; in_seq = seq1; out_seq = seq2; }
  const int kin = (layer == 0) ? N_D : N_H;
  u32* cnt_own  = cnt + (size_t)(layer * BG + b) * N_T * CPAD;
  u32* cnt_prev = (layer > 0) ? cnt + (size_t)((layer - 1) * BG + b) * N_T * CPAD : nullptr;
  u32* hsk_arr  = cnt + (size_t)(CNT_LINES + b) * CPAD;
  u32* hsk_msk  = cnt + (size_t)(CNT_LINES + BG + b) * CPAD;

  __shared__ u16   WhT[WCOL][N_H];     // [n][k], k rotated by 8*n
  __shared__ u16   WxT[WCOL][N_H];     // layer0 uses only [.][0..63]
  __shared__ float Cbuf[2][ROWS][WCOL + 1];
  __shared__ u32   fastsh;

  // ---- startup handshake: all 24 WGs of bg b on one XCD? ----
  u32 xcc;
  asm volatile("s_getreg_b32 %0, hwreg(HW_REG_XCC_ID)" : "=s"(xcc));
  if (tid == 0) {
    __hip_atomic_fetch_or(hsk_msk, 1u << (xcc & 7), __ATOMIC_RELAXED,
                          __HIP_MEMORY_SCOPE_AGENT);
    asm volatile("s_waitcnt vmcnt(0)" ::: "memory");
    __hip_atomic_fetch_add(hsk_arr, 1u, __ATOMIC_RELAXED, __HIP_MEMORY_SCOPE_AGENT);
  }

  // Stage weight slices (cols j*64..+64) while the handshake propagates.
  for (int e = tid; e < WCOL * N_H; e += 256) {
    int n = e & 63, k = e >> 6;
    WhT[n][(k + 8 * n) & (N_H - 1)] = f2bf(Wh[k * N_H + j * WCOL + n]);
  }
  for (int e = tid; e < WCOL * kin; e += 256) {
    int n = e & 63, k = e >> 6;
    WxT[n][(k + 8 * n) & (kin - 1)] = f2bf(Wx[k * N_H + j * WCOL + n]);
  }
  float bv[4];
#pragma unroll
  for (int n = 0; n < 4; ++n) bv[n] = bias[j * WCOL + n * 16 + l16];

  if (tid == 0) {
    bool f = false;
    u32 it = 0;
    while (rmw_read(hsk_arr) < (u32)HSK_TGT) {
      __builtin_amdgcn_s_sleep(1);
      if (++it > (1u << 22)) break;
    }
    if (it <= (1u << 22)) {
      u32 m = rmw_read(hsk_msk);
      f = (m != 0u) && ((m & (m - 1u)) == 0u);
    }
    fastsh = f ? 1u : 0u;
  }
  __syncthreads();
  const bool fast = (fastsh == 1u);

  const int arow = b * ROWS + half * 16 + l16;  // this lane's A-row
  bool dead = false;

  for (int t = 0; t < N_T; ++t) {
    const int par = t & 1;
    f32x4 acc[4] = {{0.f,0.f,0.f,0.f},{0.f,0.f,0.f,0.f},{0.f,0.f,0.f,0.f},{0.f,0.f,0.f,0.f}};

    if (!is_rec) {
      // ---- proj waves: (layer0: x_t@Wx) / (else: h_{l-1}(t)@Wx) -> Cbuf ----
      if (layer == 0) {
        const float* xp = x + ((size_t)arow * N_T + t) * N_D + quad * 8;
        short8 f0 = cvt8(xp), f1 = cvt8(xp + 32);
#pragma unroll
        for (int n = 0; n < 4; ++n) {
          int nl = n * 16 + l16;
          acc[n] = MFMA16(f0, ld8(&WxT[nl][(quad * 8 + 8 * nl) & (N_D - 1)]), acc[n]);
          acc[n] = MFMA16(f1, ld8(&WxT[nl][(32 + quad * 8 + 8 * nl) & (N_D - 1)]), acc[n]);
        }
      } else {
        // wait for layer l-1 to publish h(t)  [r9-proven RMW poll]
        if (lane == 0 && !dead) {
          u32* cp = cnt_prev + (size_t)t * CPAD;
          u32 it = 0;
          for (;;) {
            u32 v = fast ? rmw_read(cp)
                         : __hip_atomic_load(cp, __ATOMIC_RELAXED, __HIP_MEMORY_SCOPE_AGENT);
            if (v >= (u32)CNT_TGT) break;
            __builtin_amdgcn_s_sleep(1);
            if (++it > (1u << 22)) { dead = true; break; }
          }
        }
        const u16* sp = in_seq + ((size_t)t * N_B + arow) * N_H + quad * 8;
        i32x4 fr[16];
        if (fast) load_frags16_fast(sp, fr);
        else      load_frags16_slow(sp, fr);
#pragma unroll
        for (int kt = 0; kt < 16; ++kt) {
          short8 a = as_s8(fr[kt]);
#pragma unroll
          for (int n = 0; n < 4; ++n) {
            int nl = n * 16 + l16;
            acc[n] = MFMA16(a, ld8(&WxT[nl][(kt * 32 + quad * 8 + 8 * nl) & (N_H - 1)]), acc[n]);
          }
        }
      }
      // write proj partials to Cbuf[par]
      int rb = half * 16 + quad * 4;
#pragma unroll
      for (int n = 0; n < 4; ++n)
#pragma unroll
        for (int r = 0; r < 4; ++r)
          Cbuf[par][rb + r][n * 16 + l16] = acc[n][r];
    } else {
      // ---- rec waves: wait own layer t-1, load A, h@Wh ----
      if (t > 0) {
        if (lane == 0 && !dead) {
          u32* cp = cnt_own + (size_t)(t - 1) * CPAD;
          u32 it = 0;
          for (;;) {
            u32 v = fast ? rmw_read(cp)
                         : __hip_atomic_load(cp, __ATOMIC_RELAXED, __HIP_MEMORY_SCOPE_AGENT);
            if (v >= (u32)CNT_TGT) break;
            __builtin_amdgcn_s_sleep(1);
            if (++it > (1u << 22)) { dead = true; break; }
          }
        }
        const u16* ap = out_seq + ((size_t)(t - 1) * N_B + arow) * N_H + quad * 8;
        i32x4 fr[16];
        if (fast) load_frags16_fast(ap, fr);
        else      load_frags16_slow(ap, fr);
#pragma unroll
        for (int kt = 0; kt < 16; ++kt) {
          short8 a = as_s8(fr[kt]);
#pragma unroll
          for (int n = 0; n < 4; ++n) {
            int nl = n * 16 + l16;
            acc[n] = MFMA16(a, ld8(&WhT[nl][(kt * 32 + quad * 8 + 8 * nl) & (N_H - 1)]), acc[n]);
          }
        }
      }
    }

    __syncthreads();  // the only per-step barrier: Cbuf[par] ready

    if (is_rec) {
      // ---- combine + tanh + store h + publish ----
      int rb = half * 16 + quad * 4;
      u32 hv[4][4];
#pragma unroll
      for (int n = 0; n < 4; ++n)
#pragma unroll
        for (int r = 0; r < 4; ++r)
          hv[n][r] = (u32)f2bf(fast_tanh(acc[n][r] + Cbuf[par][rb + r][n * 16 + l16] + bv[n]));
      // lane addr: row = b*32 + half*16 + quad*4 (+r), col = j*64 + l16 (+n*16)
      u16* hdst = out_seq + ((size_t)t * N_B + b * ROWS + half * 16 + quad * 4) * N_H
                  + j * WCOL + l16;
      if (fast) {
        asm volatile(
            "global_store_short %0, %1, off sc0\n\t"
            "global_store_short %0, %2, off offset:1024 sc0\n\t"
            "global_store_short %0, %3, off offset:2048 sc0\n\t"
            "global_store_short %0, %4, off offset:3072 sc0\n\t"
            "global_store_short %0, %5, off offset:32 sc0\n\t"
            "global_store_short %0, %6, off offset:1056 sc0\n\t"
            "global_store_short %0, %7, off offset:2080 sc0\n\t"
            "global_store_short %0, %8, off offset:3104 sc0\n\t"
            "global_store_short %0, %9, off offset:64 sc0\n\t"
            "global_store_short %0, %10, off offset:1088 sc0\n\t"
            "global_store_short %0, %11, off offset:2112 sc0\n\t"
            "global_store_short %0, %12, off offset:3136 sc0\n\t"
            "global_store_short %0, %13, off offset:96 sc0\n\t"
            "global_store_short %0, %14, off offset:1120 sc0\n\t"
            "global_store_short %0, %15, off offset:2144 sc0\n\t"
            "global_store_short %0, %16, off offset:3168 sc0"
            :: "v"(hdst),
               "v"(hv[0][0]), "v"(hv[0][1]), "v"(hv[0][2]), "v"(hv[0][3]),
               "v"(hv[1][0]), "v"(hv[1][1]), "v"(hv[1][2]), "v"(hv[1][3]),
               "v"(hv[2][0]), "v"(hv[2][1]), "v"(hv[2][2]), "v"(hv[2][3]),
               "v"(hv[3][0]), "v"(hv[3][1]), "v"(hv[3][2]), "v"(hv[3][3])
            : "memory");
      } else {
        asm volatile(
            "global_store_short %0, %1, off sc0 sc1\n\t"
            "global_store_short %0, %2, off offset:1024 sc0 sc1\n\t"
            "global_store_short %0, %3, off offset:2048 sc0 sc1\n\t"
            "global_store_short %0, %4, off offset:3072 sc0 sc1\n\t"
            "global_store_short %0, %5, off offset:32 sc0 sc1\n\t"
            "global_store_short %0, %6, off offset:1056 sc0 sc1\n\t"
            "global_store_short %0, %7, off offset:2080 sc0 sc1\n\t"
            "global_store_short %0, %8, off offset:3104 sc0 sc1\n\t"
            "global_store_short %0, %9, off offset:64 sc0 sc1\n\t"
            "global_store_short %0, %10, off offset:1088 sc0 sc1\n\t"
            "global_store_short %0, %11, off offset:2112 sc0 sc1\n\t"
            "global_store_short %0, %12, off offset:3136 sc0 sc1\n\t"
            "global_store_short %0, %13, off offset:96 sc0 sc1\n\t"
            "global_store_short %0, %14, off offset:1120 sc0 sc1\n\t"
            "global_store_short %0, %15, off offset:2144 sc0 sc1\n\t"
            "global_store_short %0, %16, off offset:3168 sc0 sc1"
            :: "v"(hdst),
               "v"(hv[0][0]), "v"(hv[0][1]), "v"(hv[0][2]), "v"(hv[0][3]),
               "v"(hv[1][0]), "v"(hv[1][1]), "v"(hv[1][2]), "v"(hv[1][3]),
               "v"(hv[2][0]), "v"(hv[2][1]), "v"(hv[2][2]), "v"(hv[2][3]),
               "v"(hv[3][0]), "v"(hv[3][1]), "v"(hv[3][2]), "v"(hv[3][3])
            : "memory");
      }
      asm volatile("s_waitcnt vmcnt(0)" ::: "memory");
      if (lane == 0) {
        u32* cp = cnt_own + (size_t)t * CPAD;
        if (fast) {
          u32 one = 1u;
          asm volatile("global_atomic_add %0, %1, off" :: "v"(cp), "v"(one) : "memory");
        } else {
          __hip_atomic_fetch_add(cp, 1u, __ATOMIC_RELAXED, __HIP_MEMORY_SCOPE_AGENT);
        }
      }
    }
    // no trailing barrier: Cbuf parity + next barrier handle WAR (r8/r9-proven)
  }
}

// out[b] = seq2[T-1][b][:] . Wf + bf
__global__ void head_kernel(const u16* __restrict__ seq2, const float* __restrict__ Wf,
                            const float* __restrict__ bf, float* __restrict__ out) {
  int b    = blockIdx.x;
  int lane = threadIdx.x;  // 64
  const u16* hrow = seq2 + ((size_t)(N_T - 1) * N_B + b) * N_H;
  float s = 0.f;
#pragma unroll
  for (int r = 0; r < N_H / 64; ++r) {
    int idx = lane * 8 + r;
    s += bf2f(hrow[idx]) * Wf[idx];
  }
#pragma unroll
  for (int off = 32; off > 0; off >>= 1) s += __shfl_down(s, off);
  if (lane == 0) out[b] = s + bf[0];
}

extern "C" void kernel_launch(void* const* d_in, const int* in_sizes, int n_in,
                              void* d_out, int out_size, void* d_ws, size_t ws_size,
                              hipStream_t stream) {
  const float* x   = (const float*)d_in[0];
  const float* Wx0 = (const float*)d_in[1];
  const float* Wh0 = (const float*)d_in[2];
  const float* b0  = (const float*)d_in[3];
  const float* Wx1 = (const float*)d_in[4];
  const float* Wh1 = (const float*)d_in[5];
  const float* b1  = (const float*)d_in[6];
  const float* Wx2 = (const float*)d_in[7];
  const float* Wh2 = (const float*)d_in[8];
  const float* b2  = (const float*)d_in[9];
  const float* Wf  = (const float*)d_in[10];
  const float* bf  = (const float*)d_in[11];
  float* out = (float*)d_out;

  const size_t SEQ_BYTES = (size_t)N_T * N_B * N_H * sizeof(u16);  // 67,108,864
  if (ws_size < 3 * SEQ_BYTES + (size_t)CNT_U32 * sizeof(u32)) return;

  char* ws  = (char*)d_ws;
  u16* seq0 = (u16*)(ws);
  u16* seq1 = (u16*)(ws + SEQ_BYTES);
  u16* seq2 = (u16*)(ws + 2 * SEQ_BYTES);
  u32* cnt  = (u32*)(ws + 3 * SEQ_BYTES);

  (void)hipMemsetAsync(cnt, 0, (size_t)CNT_U32 * sizeof(u32), stream);

  rnn_pipe<<<LAY * BG * CGS, 256, 0, stream>>>(x, Wx0, Wh0, b0, Wx1, Wh1, b1,
                                               Wx2, Wh2, b2, seq0, seq1, seq2,
                                               cnt);
  head_kernel<<<N_B, 64, 0, stream>>>(seq2, Wf, bf, out);
}

// Round 14
// 1218.091 us; speedup vs baseline: 2.7057x; 1.0116x over previous
//
#include <hip/hip_runtime.h>

// ---------------------------------------------------------------------------
// RNN_69526930588180: 3-layer SimpleRNN (tanh), B=256, T=256, D=64, H=512.
//
// Round 14 = round 13 (1232us best: r9 pipeline + padded counter lines) with
// per-line atomic traffic halved via intra-WG LDS flags (CU-coherent, ~50cyc):
//  * ONE poller per WG per dependency: rec wave0 polls (RMW, the only safe
//    poll — r7/r12 proved both plain-store publish and plain-load poll fail);
//    rec wave1 spins on an LDS flag. Proj w2 polls, w3 spins.  16 -> 8
//    pollers per counter line.
//  * ONE publisher per WG: wave1 signals stores-drained via LDS flag after
//    its vmcnt(0); wave0 spins the flag then issues a single atomic add.
//    Publishers 16 -> 8, CNT_TGT 16 -> 8.
//  * poll backoff: first 2 iterations without s_sleep.
// Everything else verbatim r13: 192 WGs = 3 layers x 8 bg x 8 cg; fast
// (same-XCD)=sc0, slow=sc0 sc1; XCC_ID handshake; Cbuf parity; 1 barrier/step.
// ---------------------------------------------------------------------------

typedef unsigned short u16;
typedef unsigned int   u32;

typedef __attribute__((ext_vector_type(8))) short short8;
typedef __attribute__((ext_vector_type(4))) float f32x4;
typedef __attribute__((ext_vector_type(4))) int   i32x4;

#define N_B 256
#define N_T 256
#define N_D 64
#define N_H 512
#define LAY 3
#define BG  8     // batch groups (32 rows each)
#define CGS 8     // col groups (64 cols each)
#define ROWS 32   // rows per bg
#define WCOL 64   // cols per WG
#define CNT_TGT 8    // 8 WGs publish once per (layer,bg,t)
#define HSK_TGT 24   // 3 layers x 8 cg WGs per bg
#define CPAD 16      // u32 per counter (64B line)
#define CNT_LINES (LAY * BG * N_T)
#define CNT_U32   ((CNT_LINES + 2 * BG) * CPAD)
#define SPIN_LIM (1u << 22)

__device__ __forceinline__ u16 f2bf(float f) {
  union { float f; u32 u; } v; v.f = f;
  u32 u = v.u;
  u += 0x7fffu + ((u >> 16) & 1u);   // RNE
  return (u16)(u >> 16);
}
__device__ __forceinline__ float bf2f(u16 h) {
  union { u32 u; float f; } v; v.u = ((u32)h) << 16;
  return v.f;
}
__device__ __forceinline__ short8 ld8(const u16* p) { return *(const short8*)p; }
__device__ __forceinline__ short8 cvt8(const float* p) {
  short8 r;
#pragma unroll
  for (int j = 0; j < 8; ++j) r[j] = (short)f2bf(p[j]);
  return r;
}
__device__ __forceinline__ short8 as_s8(i32x4 v) {
  union { i32x4 i; short8 s; } u; u.i = v; return u.s;
}
__device__ __forceinline__ float fast_tanh(float x) {
  float xc = fminf(fmaxf(x, -9.f), 9.f);
  float e  = __builtin_amdgcn_exp2f(xc * 2.8853900817779268f);
  return 1.f - 2.f * __builtin_amdgcn_rcpf(e + 1.f);
}
// FIFO-fair coherence-point read (r6/r9/r13-proven). The ONLY safe poll.
__device__ __forceinline__ u32 rmw_read(u32* p) {
  u32 v, z = 0;
  asm volatile("global_atomic_add %0, %1, %2, off sc0\n\ts_waitcnt vmcnt(0)"
               : "=v"(v) : "v"(p), "v"(z) : "memory");
  return v;
}
// Global counter poll (lane0 of one wave only).
__device__ __forceinline__ void poll_cnt(u32* cp, u32 target, bool fast, bool* dead) {
  u32 it = 0;
  for (;;) {
    u32 v = fast ? rmw_read(cp)
                 : __hip_atomic_load(cp, __ATOMIC_RELAXED, __HIP_MEMORY_SCOPE_AGENT);
    if (v >= target) return;
    if (it >= 2) __builtin_amdgcn_s_sleep(1);
    if (++it > SPIN_LIM) { *dead = true; return; }
  }
}
// LDS flag ops (CU-coherent): set / spin-until-equal.
__device__ __forceinline__ void lds_set(volatile u32* f, u32 v) {
  __hip_atomic_store((u32*)f, v, __ATOMIC_RELEASE, __HIP_MEMORY_SCOPE_WORKGROUP);
}
__device__ __forceinline__ void lds_wait(volatile u32* f, u32 want, bool* dead) {
  u32 it = 0;
  while (__hip_atomic_load((u32*)f, __ATOMIC_ACQUIRE, __HIP_MEMORY_SCOPE_WORKGROUP) != want) {
    if (++it > SPIN_LIM) { *dead = true; return; }
  }
}

// 16 batched A-fragment loads (row fixed, k = kt*32 + quad*8), one vmcnt.
__device__ __forceinline__ void load_frags16_fast(const u16* p, i32x4 f[16]) {
  asm volatile(
      "global_load_dwordx4 %0, %16, off sc0\n\t"
      "global_load_dwordx4 %1, %16, off offset:64 sc0\n\t"
      "global_load_dwordx4 %2, %16, off offset:128 sc0\n\t"
      "global_load_dwordx4 %3, %16, off offset:192 sc0\n\t"
      "global_load_dwordx4 %4, %16, off offset:256 sc0\n\t"
      "global_load_dwordx4 %5, %16, off offset:320 sc0\n\t"
      "global_load_dwordx4 %6, %16, off offset:384 sc0\n\t"
      "global_load_dwordx4 %7, %16, off offset:448 sc0\n\t"
      "global_load_dwordx4 %8, %16, off offset:512 sc0\n\t"
      "global_load_dwordx4 %9, %16, off offset:576 sc0\n\t"
      "global_load_dwordx4 %10, %16, off offset:640 sc0\n\t"
      "global_load_dwordx4 %11, %16, off offset:704 sc0\n\t"
      "global_load_dwordx4 %12, %16, off offset:768 sc0\n\t"
      "global_load_dwordx4 %13, %16, off offset:832 sc0\n\t"
      "global_load_dwordx4 %14, %16, off offset:896 sc0\n\t"
      "global_load_dwordx4 %15, %16, off offset:960 sc0\n\t"
      "s_waitcnt vmcnt(0)"
      : "=&v"(f[0]), "=&v"(f[1]), "=&v"(f[2]), "=&v"(f[3]),
        "=&v"(f[4]), "=&v"(f[5]), "=&v"(f[6]), "=&v"(f[7]),
        "=&v"(f[8]), "=&v"(f[9]), "=&v"(f[10]), "=&v"(f[11]),
        "=&v"(f[12]), "=&v"(f[13]), "=&v"(f[14]), "=&v"(f[15])
      : "v"(p) : "memory");
}
__device__ __forceinline__ void load_frags16_slow(const u16* p, i32x4 f[16]) {
  asm volatile(
      "global_load_dwordx4 %0, %16, off sc0 sc1\n\t"
      "global_load_dwordx4 %1, %16, off offset:64 sc0 sc1\n\t"
      "global_load_dwordx4 %2, %16, off offset:128 sc0 sc1\n\t"
      "global_load_dwordx4 %3, %16, off offset:192 sc0 sc1\n\t"
      "global_load_dwordx4 %4, %16, off offset:256 sc0 sc1\n\t"
      "global_load_dwordx4 %5, %16, off offset:320 sc0 sc1\n\t"
      "global_load_dwordx4 %6, %16, off offset:384 sc0 sc1\n\t"
      "global_load_dwordx4 %7, %16, off offset:448 sc0 sc1\n\t"
      "global_load_dwordx4 %8, %16, off offset:512 sc0 sc1\n\t"
      "global_load_dwordx4 %9, %16, off offset:576 sc0 sc1\n\t"
      "global_load_dwordx4 %10, %16, off offset:640 sc0 sc1\n\t"
      "global_load_dwordx4 %11, %16, off offset:704 sc0 sc1\n\t"
      "global_load_dwordx4 %12, %16, off offset:768 sc0 sc1\n\t"
      "global_load_dwordx4 %13, %16, off offset:832 sc0 sc1\n\t"
      "global_load_dwordx4 %14, %16, off offset:896 sc0 sc1\n\t"
      "global_load_dwordx4 %15, %16, off offset:960 sc0 sc1\n\t"
      "s_waitcnt vmcnt(0)"
      : "=&v"(f[0]), "=&v"(f[1]), "=&v"(f[2]), "=&v"(f[3]),
        "=&v"(f[4]), "=&v"(f[5]), "=&v"(f[6]), "=&v"(f[7]),
        "=&v"(f[8]), "=&v"(f[9]), "=&v"(f[10]), "=&v"(f[11]),
        "=&v"(f[12]), "=&v"(f[13]), "=&v"(f[14]), "=&v"(f[15])
      : "v"(p) : "memory");
}

#define MFMA16(a, b, c) __builtin_amdgcn_mfma_f32_16x16x32_bf16((a), (b), (c), 0, 0, 0)

// All 3 layers in one persistent kernel (layer-wavefront pipeline).
__global__ __launch_bounds__(256, 1)
void rnn_pipe(const float* __restrict__ x,
              const float* __restrict__ Wx0, const float* __restrict__ Wh0, const float* __restrict__ b0,
              const float* __restrict__ Wx1, const float* __restrict__ Wh1, const float* __restrict__ b1,
              const float* __restrict__ Wx2, const float* __restrict__ Wh2, const float* __restrict__ b2,
              u16* __restrict__ seq0, u16* __restrict__ seq1, u16* __restrict__ seq2,
              u32* __restrict__ cnt) {
  const int b    = blockIdx.x & 7;          // batch group (XCD under %8 rr)
  const int rst  = blockIdx.x >> 3;         // 0..23
  const int layer = rst >> 3;               // 0..2
  const int j    = rst & 7;                 // col group
  const int tid  = threadIdx.x;
  const int lane = tid & 63;
  const int w    = tid >> 6;                // 0-1 rec, 2-3 proj
  const int quad = lane >> 4;
  const int l16  = lane & 15;
  const int half = w & 1;                   // 16-row sub-tile
  const bool is_rec = (w < 2);

  const float *Wx, *Wh, *bias; const u16 *in_seq = nullptr; u16 *out_seq;
  if (layer == 0)      { Wx = Wx0; Wh = Wh0; bias = b0; out_seq = seq0; }
  else if (layer == 1) { Wx = Wx1; Wh = Wh1; bias = b1; in_seq = seq0; out_seq = seq1; }
  else                 { Wx = Wx2; Wh = Wh2; bias = b2; in_seq = seq1; out_seq = seq2; }
  const int kin = (layer == 0) ? N_D : N_H;
  u32* cnt_own  = cnt + (size_t)(layer * BG + b) * N_T * CPAD;
  u32* cnt_prev = (layer > 0) ? cnt + (size_t)((layer - 1) * BG + b) * N_T * CPAD : nullptr;
  u32* hsk_arr  = cnt + (size_t)(CNT_LINES + b) * CPAD;
  u32* hsk_msk  = cnt + (size_t)(CNT_LINES + BG + b) * CPAD;

  __shared__ u16   WhT[WCOL][N_H];     // [n][k], k rotated by 8*n
  __shared__ u16   WxT[WCOL][N_H];     // layer0 uses only [.][0..63]
  __shared__ float Cbuf[2][ROWS][WCOL + 1];
  __shared__ u32   fastsh;
  __shared__ u32   sflags[6];          // [0..1] rec-rdy par, [2..3] proj-rdy par, [4..5] pub par

  // ---- startup handshake: all 24 WGs of bg b on one XCD? ----
  u32 xcc;
  asm volatile("s_getreg_b32 %0, hwreg(HW_REG_XCC_ID)" : "=s"(xcc));
  if (tid == 0) {
    __hip_atomic_fetch_or(hsk_msk, 1u << (xcc & 7), __ATOMIC_RELAXED,
                          __HIP_MEMORY_SCOPE_AGENT);
    asm volatile("s_waitcnt vmcnt(0)" ::: "memory");
    __hip_atomic_fetch_add(hsk_arr, 1u, __ATOMIC_RELAXED, __HIP_MEMORY_SCOPE_AGENT);
  }
  if (tid < 6) sflags[tid] = 0;

  // Stage weight slices (cols j*64..+64) while the handshake propagates.
  for (int e = tid; e < WCOL * N_H; e += 256) {
    int n = e & 63, k = e >> 6;
    WhT[n][(k + 8 * n) & (N_H - 1)] = f2bf(Wh[k * N_H + j * WCOL + n]);
  }
  for (int e = tid; e < WCOL * kin; e += 256) {
    int n = e & 63, k = e >> 6;
    WxT[n][(k + 8 * n) & (kin - 1)] = f2bf(Wx[k * N_H + j * WCOL + n]);
  }
  float bv[4];
#pragma unroll
  for (int n = 0; n < 4; ++n) bv[n] = bias[j * WCOL + n * 16 + l16];

  if (tid == 0) {
    bool f = false;
    u32 it = 0;
    while (rmw_read(hsk_arr) < (u32)HSK_TGT) {
      __builtin_amdgcn_s_sleep(1);
      if (++it > SPIN_LIM) break;
    }
    if (it <= SPIN_LIM) {
      u32 m = rmw_read(hsk_msk);
      f = (m != 0u) && ((m & (m - 1u)) == 0u);
    }
    fastsh = f ? 1u : 0u;
  }
  __syncthreads();
  const bool fast = (fastsh == 1u);

  const int arow = b * ROWS + half * 16 + l16;  // this lane's A-row
  bool dead = false;

  for (int t = 0; t < N_T; ++t) {
    const int par = t & 1;
    f32x4 acc[4] = {{0.f,0.f,0.f,0.f},{0.f,0.f,0.f,0.f},{0.f,0.f,0.f,0.f},{0.f,0.f,0.f,0.f}};

    if (!is_rec) {
      // ---- proj waves: (layer0: x_t@Wx) / (else: h_{l-1}(t)@Wx) -> Cbuf ----
      if (layer == 0) {
        const float* xp = x + ((size_t)arow * N_T + t) * N_D + quad * 8;
        short8 f0 = cvt8(xp), f1 = cvt8(xp + 32);
#pragma unroll
        for (int n = 0; n < 4; ++n) {
          int nl = n * 16 + l16;
          acc[n] = MFMA16(f0, ld8(&WxT[nl][(quad * 8 + 8 * nl) & (N_D - 1)]), acc[n]);
          acc[n] = MFMA16(f1, ld8(&WxT[nl][(32 + quad * 8 + 8 * nl) & (N_D - 1)]), acc[n]);
        }
      } else {
        // ONE poller (w2); w3 spins on LDS flag.
        if (half == 0) {
          if (lane == 0) {
            if (!dead) poll_cnt(cnt_prev + (size_t)t * CPAD, CNT_TGT, fast, &dead);
            lds_set(&sflags[2 + par], (u32)(t + 1));
          }
        } else {
          if (lane == 0 && !dead) lds_wait(&sflags[2 + par], (u32)(t + 1), &dead);
        }
        const u16* sp = in_seq + ((size_t)t * N_B + arow) * N_H + quad * 8;
        i32x4 fr[16];
        if (fast) load_frags16_fast(sp, fr);
        else      load_frags16_slow(sp, fr);
#pragma unroll
        for (int kt = 0; kt < 16; ++kt) {
          short8 a = as_s8(fr[kt]);
#pragma unroll
          for (int n = 0; n < 4; ++n) {
            int nl = n * 16 + l16;
            acc[n] = MFMA16(a, ld8(&WxT[nl][(kt * 32 + quad * 8 + 8 * nl) & (N_H - 1)]), acc[n]);
          }
        }
      }
      // write proj partials to Cbuf[par]
      int rb = half * 16 + quad * 4;
#pragma unroll
      for (int n = 0; n < 4; ++n)
#pragma unroll
        for (int r = 0; r < 4; ++r)
          Cbuf[par][rb + r][n * 16 + l16] = acc[n][r];
    } else {
      // ---- rec waves: wait own layer t-1 (ONE poller: wave0), load A, h@Wh ----
      if (t > 0) {
        if (half == 0) {
          if (lane == 0) {
            if (!dead) poll_cnt(cnt_own + (size_t)(t - 1) * CPAD, CNT_TGT, fast, &dead);
            lds_set(&sflags[par], (u32)t);
          }
        } else {
          if (lane == 0 && !dead) lds_wait(&sflags[par], (u32)t, &dead);
        }
        const u16* ap = out_seq + ((size_t)(t - 1) * N_B + arow) * N_H + quad * 8;
        i32x4 fr[16];
        if (fast) load_frags16_fast(ap, fr);
        else      load_frags16_slow(ap, fr);
#pragma unroll
        for (int kt = 0; kt < 16; ++kt) {
          short8 a = as_s8(fr[kt]);
#pragma unroll
          for (int n = 0; n < 4; ++n) {
            int nl = n * 16 + l16;
            acc[n] = MFMA16(a, ld8(&WhT[nl][(kt * 32 + quad * 8 + 8 * nl) & (N_H - 1)]), acc[n]);
          }
        }
      }
    }

    __syncthreads();  // the only per-step barrier: Cbuf[par] ready

    if (is_rec) {
      // ---- combine + tanh + store h; ONE publish per WG ----
      int rb = half * 16 + quad * 4;
      u32 hv[4][4];
#pragma unroll
      for (int n = 0; n < 4; ++n)
#pragma unroll
        for (int r = 0; r < 4; ++r)
          hv[n][r] = (u32)f2bf(fast_tanh(acc[n][r] + Cbuf[par][rb + r][n * 16 + l16] + bv[n]));
      // lane addr: row = b*32 + half*16 + quad*4 (+r), col = j*64 + l16 (+n*16)
      u16* hdst = out_seq + ((size_t)t * N_B + b * ROWS + half * 16 + quad * 4) * N_H
                  + j * WCOL + l16;
      if (fast) {
        asm volatile(
            "global_store_short %0, %1, off sc0\n\t"
            "global_store_short %0, %2, off offset:1024 sc0\n\t"
            "global_store_short %0, %3, off offset:2048 sc0\n\t"
            "global_store_short %0, %4, off offset:3072 sc0\n\t"
            "global_store_short %0, %5, off offset:32 sc0\n\t"
            "global_store_short %0, %6, off offset:1056 sc0\n\t"
            "global_store_short %0, %7, off offset:2080 sc0\n\t"
            "global_store_short %0, %8, off offset:3104 sc0\n\t"
            "global_store_short %0, %9, off offset:64 sc0\n\t"
            "global_store_short %0, %10, off offset:1088 sc0\n\t"
            "global_store_short %0, %11, off offset:2112 sc0\n\t"
            "global_store_short %0, %12, off offset:3136 sc0\n\t"
            "global_store_short %0, %13, off offset:96 sc0\n\t"
            "global_store_short %0, %14, off offset:1120 sc0\n\t"
            "global_store_short %0, %15, off offset:2144 sc0\n\t"
            "global_store_short %0, %16, off offset:3168 sc0"
            :: "v"(hdst),
               "v"(hv[0][0]), "v"(hv[0][1]), "v"(hv[0][2]), "v"(hv[0][3]),
               "v"(hv[1][0]), "v"(hv[1][1]), "v"(hv[1][2]), "v"(hv[1][3]),
               "v"(hv[2][0]), "v"(hv[2][1]), "v"(hv[2][2]), "v"(hv[2][3]),
               "v"(hv[3][0]), "v"(hv[3][1]), "v"(hv[3][2]), "v"(hv[3][3])
            : "memory");
      } else {
        asm volatile(
            "global_store_short %0, %1, off sc0 sc1\n\t"
            "global_store_short %0, %2, off offset:1024 sc0 sc1\n\t"
            "global_store_short %0, %3, off offset:2048 sc0 sc1\n\t"
            "global_store_short %0, %4, off offset:3072 sc0 sc1\n\t"
            "global_store_short %0, %5, off offset:32 sc0 sc1\n\t"
            "global_store_short %0, %6, off offset:1056 sc0 sc1\n\t"
            "global_store_short %0, %7, off offset:2080 sc0 sc1\n\t"
            "global_store_short %0, %8, off offset:3104 sc0 sc1\n\t"
            "global_store_short %0, %9, off offset:64 sc0 sc1\n\t"
            "global_store_short %0, %10, off offset:1088 sc0 sc1\n\t"
            "global_store_short %0, %11, off offset:2112 sc0 sc1\n\t"
            "global_store_short %0, %12, off offset:3136 sc0 sc1\n\t"
            "global_store_short %0, %13, off offset:96 sc0 sc1\n\t"
            "global_store_short %0, %14, off offset:1120 sc0 sc1\n\t"
            "global_store_short %0, %15, off offset:2144 sc0 sc1\n\t"
            "global_store_short %0, %16, off offset:3168 sc0 sc1"
            :: "v"(hdst),
               "v"(hv[0][0]), "v"(hv[0][1]), "v"(hv[0][2]), "v"(hv[0][3]),
               "v"(hv[1][0]), "v"(hv[1][1]), "v"(hv[1][2]), "v"(hv[1][3]),
               "v"(hv[2][0]), "v"(hv[2][1]), "v"(hv[2][2]), "v"(hv[2][3]),
               "v"(hv[3][0]), "v"(hv[3][1]), "v"(hv[3][2]), "v"(hv[3][3])
            : "memory");
      }
      asm volatile("s_waitcnt vmcnt(0)" ::: "memory");  // this wave's stores acked
      if (half == 1) {
        if (lane == 0) lds_set(&sflags[4 + par], (u32)(t + 1));   // wave1 drained
      } else {
        if (lane == 0) {
          if (!dead) lds_wait(&sflags[4 + par], (u32)(t + 1), &dead);  // both drained
          u32* cp = cnt_own + (size_t)t * CPAD;
          if (fast) {
            u32 one = 1u;
            asm volatile("global_atomic_add %0, %1, off" :: "v"(cp), "v"(one) : "memory");
          } else {
            __hip_atomic_fetch_add(cp, 1u, __ATOMIC_RELAXED, __HIP_MEMORY_SCOPE_AGENT);
          }
        }
      }
    }
    // no trailing barrier: Cbuf parity + next barrier handle WAR (r8/r9-proven)
  }
}

// out[b] = seq2[T-1][b][:] . Wf + bf
__global__ void head_kernel(const u16* __restrict__ seq2, const float* __restrict__ Wf,
                            const float* __restrict__ bf, float* __restrict__ out) {
  int b    = blockIdx.x;
  int lane = threadIdx.x;  // 64
  const u16* hrow = seq2 + ((size_t)(N_T - 1) * N_B + b) * N_H;
  float s = 0.f;
#pragma unroll
  for (int r = 0; r < N_H / 64; ++r) {
    int idx = lane * 8 + r;
    s += bf2f(hrow[idx]) * Wf[idx];
  }
#pragma unroll
  for (int off = 32; off > 0; off >>= 1) s += __shfl_down(s, off);
  if (lane == 0) out[b] = s + bf[0];
}

extern "C" void kernel_launch(void* const* d_in, const int* in_sizes, int n_in,
                              void* d_out, int out_size, void* d_ws, size_t ws_size,
                              hipStream_t stream) {
  const float* x   = (const float*)d_in[0];
  const float* Wx0 = (const float*)d_in[1];
  const float* Wh0 = (const float*)d_in[2];
  const float* b0  = (const float*)d_in[3];
  const float* Wx1 = (const float*)d_in[4];
  const float* Wh1 = (const float*)d_in[5];
  const float* b1  = (const float*)d_in[6];
  const float* Wx2 = (const float*)d_in[7];
  const float* Wh2 = (const float*)d_in[8];
  const float* b2  = (const float*)d_in[9];
  const float* Wf  = (const float*)d_in[10];
  const float* bf  = (const float*)d_in[11];
  float* out = (float*)d_out;

  const size_t SEQ_BYTES = (size_t)N_T * N_B * N_H * sizeof(u16);  // 67,108,864
  if (ws_size < 3 * SEQ_BYTES + (size_t)CNT_U32 * sizeof(u32)) return;

  char* ws  = (char*)d_ws;
  u16* seq0 = (u16*)(ws);
  u16* seq1 = (u16*)(ws + SEQ_BYTES);
  u16* seq2 = (u16*)(ws + 2 * SEQ_BYTES);
  u32* cnt  = (u32*)(ws + 3 * SEQ_BYTES);

  (void)hipMemsetAsync(cnt, 0, (size_t)CNT_U32 * sizeof(u32), stream);

  rnn_pipe<<<LAY * BG * CGS, 256, 0, stream>>>(x, Wx0, Wh0, b0, Wx1, Wh1, b1,
                                               Wx2, Wh2, b2, seq0, seq1, seq2,
                                               cnt);
  head_kernel<<<N_B, 64, 0, stream>>>(seq2, Wf, bf, out);
}